// Round 2
// baseline (306.687 us; speedup 1.0000x reference)
//
#include <hip/hip_runtime.h>
#include <hip/hip_bf16.h>

// Problem constants
#define T_STEPS 24
#define NB      512      // N
#define HID     128
#define INDIM   64
#define BN      16384    // B*N rows

typedef __bf16 bf16_t;
typedef __bf16 bf16x8 __attribute__((ext_vector_type(8)));
typedef float  f32x16 __attribute__((ext_vector_type(16)));

__device__ __forceinline__ float sigm_(float x)  { return 1.f / (1.f + __expf(-x)); }
__device__ __forceinline__ float tanh_(float x)  { float e = __expf(-2.f * x); return (1.f - e) / (1.f + e); }

// ---------------------------------------------------------------------------
// Pack kernel: builds
//  WgP: frag-ordered B' [16 coltiles][16 ksteps][64 lanes][8 bf16]  (512x256 logical)
//       cols   0..127 : r    = [W_ih_r | W_hh_r]
//       cols 128..255 : z    = [W_ih_z | W_hh_z]
//       cols 256..383 : i_n  = [W_ih_n | 0]
//       cols 384..511 : h_n  = [0      | W_hh_n]
//  WmP: frag-ordered W_mlp [4 coltiles][4 ksteps][64][8]           (128x64 logical)
//  bc : combined biases [512] fp32
// ---------------------------------------------------------------------------
__global__ void pack_kernel(const float* __restrict__ Wm,
                            const float* __restrict__ Wih, const float* __restrict__ Whh,
                            const float* __restrict__ bih, const float* __restrict__ bhh,
                            bf16_t* __restrict__ WgP, bf16_t* __restrict__ WmP,
                            float* __restrict__ bc)
{
    int tid = blockIdx.x * 256 + threadIdx.x;
    if (tid < 131072) {                    // WgP
        int e  = tid & 7;
        int l  = (tid >> 3) & 63;
        int ks = (tid >> 9) & 15;
        int ct = tid >> 13;
        int col = ct * 32 + (l & 31);      // 0..511
        int k   = ks * 16 + ((l >> 5) << 3) + e;   // 0..255
        float v;
        if (col < 256)      v = (k < 128) ? Wih[col * 128 + k] : Whh[col * 128 + (k - 128)];
        else if (col < 384) v = (k < 128) ? Wih[col * 128 + k] : 0.f;
        else                v = (k < 128) ? 0.f : Whh[(col - 128) * 128 + (k - 128)];
        WgP[tid] = (bf16_t)v;
    } else if (tid < 139264) {             // WmP
        int u  = tid - 131072;
        int e  = u & 7;
        int l  = (u >> 3) & 63;
        int ks = (u >> 9) & 3;
        int ct = u >> 11;
        int col = ct * 32 + (l & 31);      // 0..127
        int k   = ks * 16 + ((l >> 5) << 3) + e;   // 0..63
        WmP[u] = (bf16_t)Wm[col * 64 + k];
    } else if (tid < 139776) {             // bc
        int j = tid - 139264;              // 0..511
        float v;
        if (j < 256)      v = bih[j] + bhh[j];
        else if (j < 384) v = bih[j];
        else              v = bhh[j - 128];
        bc[j] = v;
    }
}

// ---------------------------------------------------------------------------
// Fused per-time-step kernel: emb = relu(x_t @ Wm^T + bm);
// S = [emb|h] @ B'^T ; gates; h_new.  32 rows/block, 256 threads (4 waves).
// ---------------------------------------------------------------------------
__global__ __launch_bounds__(256) void gru_step(
    const float*  __restrict__ x, int t,
    const float*  __restrict__ h32_in, float* __restrict__ h32_out,
    const bf16_t* __restrict__ WgP, const bf16_t* __restrict__ WmP,
    const float*  __restrict__ bc,  const float* __restrict__ bm)
{
    __shared__ char xs[32 * 256];   // x tile, bf16, XOR-swizzled rows of 256B
    __shared__ char es[32 * 256];   // emb tile, bf16, swizzled
    __shared__ char hs[32 * 256];   // h tile, bf16, swizzled (128 bf16/row)
    const int tid = threadIdx.x;
    const int l   = tid & 63;
    const int w   = tid >> 6;
    const int r0  = blockIdx.x * 32;

    // ---- stage x tile (fp32 -> bf16) and h tile (fp32 -> bf16) into swizzled LDS
    {
        const int b = r0 >> 9, n0 = r0 & (NB - 1);
        const float* xsrc = x + ((size_t)(b * T_STEPS + t) * NB + n0) * INDIM;
        #pragma unroll
        for (int c0 = 0; c0 < 2; ++c0) {
            int c = c0 * 256 + tid;            // float4 chunk in [0,512)
            int row = c >> 4, k4 = c & 15;     // 16 float4 per 64-float row
            float4 v = ((const float4*)xsrc)[c];
            union { bf16_t h[4]; unsigned int u[2]; } p;
            p.h[0] = (bf16_t)v.x; p.h[1] = (bf16_t)v.y;
            p.h[2] = (bf16_t)v.z; p.h[3] = (bf16_t)v.w;
            *(uint2*)(xs + row * 256 + ((k4 * 8) ^ ((row & 15) << 4))) = make_uint2(p.u[0], p.u[1]);
        }
        const float4* hsrc = (const float4*)(h32_in + (size_t)r0 * HID);
        #pragma unroll
        for (int c0 = 0; c0 < 4; ++c0) {
            int c = c0 * 256 + tid;            // float4 chunk in [0,1024)
            int row = c >> 5, k4 = c & 31;     // 32 float4 per 128-float row
            float4 v = hsrc[c];
            union { bf16_t h[4]; unsigned int u[2]; } p;
            p.h[0] = (bf16_t)v.x; p.h[1] = (bf16_t)v.y;
            p.h[2] = (bf16_t)v.z; p.h[3] = (bf16_t)v.w;
            *(uint2*)(hs + row * 256 + ((k4 * 8) ^ ((row & 15) << 4))) = make_uint2(p.u[0], p.u[1]);
        }
    }
    __syncthreads();

    const int rowA = l & 31;
    const int swz  = (rowA & 15) << 4;
    const int hi16 = (l >> 5) << 4;            // 0 or 16 bytes within k-chunk

    // ---- phase A: emb coltile w (32 cols), K=64 over x
    f32x16 accA = {};
    #pragma unroll
    for (int ks = 0; ks < 4; ++ks) {
        bf16x8 a   = *(const bf16x8*)(xs + rowA * 256 + ((ks * 32 + hi16) ^ swz));
        bf16x8 bfr = *(const bf16x8*)(WmP + (w * 4 + ks) * 512 + l * 8);
        accA = __builtin_amdgcn_mfma_f32_32x32x16_bf16(a, bfr, accA, 0, 0, 0);
    }
    {   // bias + relu -> es (bf16, swizzled). C layout: col=l&31, row=(q&3)+8(q>>2)+4(l>>5)
        const int col = w * 32 + (l & 31);
        const float bmv = bm[col];
        #pragma unroll
        for (int q = 0; q < 16; ++q) {
            int row = (q & 3) + ((q >> 2) << 3) + ((l >> 5) << 2);
            float v = fmaxf(accA[q] + bmv, 0.f);
            *(bf16_t*)(es + row * 256 + ((col * 2) ^ ((row & 15) << 4))) = (bf16_t)v;
        }
    }
    __syncthreads();

    // ---- phase B: S = [emb|h] @ B'^T. Wave w owns coltiles {w, w+4, w+8, w+12}
    f32x16 ac0 = {}, ac1 = {}, ac2 = {}, ac3 = {};
    #pragma unroll
    for (int ks = 0; ks < 16; ++ks) {
        const char* src = (ks < 8) ? es : hs;
        bf16x8 a = *(const bf16x8*)(src + rowA * 256 + (((ks & 7) * 32 + hi16) ^ swz));
        const bf16_t* wb = WgP + ks * 512 + l * 8;
        bf16x8 b0 = *(const bf16x8*)(wb + (w     ) * 16 * 512);
        bf16x8 b1 = *(const bf16x8*)(wb + (w +  4) * 16 * 512);
        bf16x8 b2 = *(const bf16x8*)(wb + (w +  8) * 16 * 512);
        bf16x8 b3 = *(const bf16x8*)(wb + (w + 12) * 16 * 512);
        ac0 = __builtin_amdgcn_mfma_f32_32x32x16_bf16(a, b0, ac0, 0, 0, 0);
        ac1 = __builtin_amdgcn_mfma_f32_32x32x16_bf16(a, b1, ac1, 0, 0, 0);
        ac2 = __builtin_amdgcn_mfma_f32_32x32x16_bf16(a, b2, ac2, 0, 0, 0);
        ac3 = __builtin_amdgcn_mfma_f32_32x32x16_bf16(a, b3, ac3, 0, 0, 0);
    }

    // ---- phase C: gates (lane-local) + h update
    {
        const int jh = w * 32 + (l & 31);
        const float bR  = bc[jh];
        const float bZ  = bc[HID + jh];
        const float bIN = bc[2 * HID + jh];
        const float bHN = bc[3 * HID + jh];
        #pragma unroll
        for (int q = 0; q < 16; ++q) {
            int rowL = (q & 3) + ((q >> 2) << 3) + ((l >> 5) << 2);
            size_t gro = (size_t)(r0 + rowL) * HID + jh;
            float r  = sigm_(ac0[q] + bR);
            float z  = sigm_(ac1[q] + bZ);
            float hn = ac3[q] + bHN;
            float n  = tanh_(ac2[q] + bIN + r * hn);
            float hold = h32_in[gro];
            float hnew = (1.f - z) * n + z * hold;
            h32_out[gro] = hnew;
        }
    }
}

// ---------------------------------------------------------------------------
extern "C" void kernel_launch(void* const* d_in, const int* in_sizes, int n_in,
                              void* d_out, int out_size, void* d_ws, size_t ws_size,
                              hipStream_t stream)
{
    const float* x   = (const float*)d_in[0];
    const float* Wm  = (const float*)d_in[1];
    const float* bm  = (const float*)d_in[2];
    const float* Wih = (const float*)d_in[3];
    const float* Whh = (const float*)d_in[4];
    const float* bih = (const float*)d_in[5];
    const float* bhh = (const float*)d_in[6];

    char* ws = (char*)d_ws;
    const size_t SZ_H32 = (size_t)BN * HID * 4;   // 8 MiB
    // d_out doubles as h32a (exactly BN*HID fp32): odd steps write it, so
    // step t=23 deposits the final hidden state directly in d_out.
    float*  h32a = (float*)d_out;
    float*  h32b = (float*)(ws);
    bf16_t* WgP  = (bf16_t*)(ws + SZ_H32);
    bf16_t* WmP  = (bf16_t*)(ws + SZ_H32 + 262144);
    float*  bcp  = (float*) (ws + SZ_H32 + 262144 + 16384);

    // zero initial hidden state every call (deterministic; d_out is poisoned)
    hipMemsetAsync(h32a, 0, SZ_H32, stream);

    pack_kernel<<<547, 256, 0, stream>>>(Wm, Wih, Whh, bih, bhh, WgP, WmP, bcp);

    float* h32_in = h32a;  float* h32_out = h32b;
    for (int t = 0; t < T_STEPS; ++t) {
        gru_step<<<512, 256, 0, stream>>>(x, t, h32_in, h32_out, WgP, WmP, bcp, bm);
        float* tmp = h32_in; h32_in = h32_out; h32_out = tmp;
    }
}

// Round 3
// 280.506 us; speedup vs baseline: 1.0933x; 1.0933x over previous
//
#include <hip/hip_runtime.h>
#include <hip/hip_bf16.h>

#define T_STEPS 24
#define NB      512
#define HID     128
#define INDIM   64
#define BN      16384

typedef __bf16 bf16_t;
typedef __bf16 bf16x8 __attribute__((ext_vector_type(8)));
typedef float  f32x16 __attribute__((ext_vector_type(16)));

__device__ __forceinline__ float sigm_(float x)  { return 1.f / (1.f + __expf(-x)); }
__device__ __forceinline__ float tanh_(float x)  { float e = __expf(-2.f * x); return (1.f - e) / (1.f + e); }

// ---------------------------------------------------------------------------
// Pack kernel. Frag layout everywhere: [ct][ks][64 lanes][8 bf16], frag = 512 elems.
//  Wrz [8ct][16ks]: cols 0..255 = [r|z], K=256 = [emb(128)|h(128)]
//  Win [4ct][8ks]:  cols 0..127 = i_n rows of Wih (256..383), K=128 (emb)
//  Whn [4ct][8ks]:  cols 0..127 = h_n rows of Whh (256..383), K=128 (h)
//  WmP [4ct][4ks]:  cols 0..127 = W_mlp, K=64 (x)
//  bc  [512] f32:   [0..255]=bih+bhh (rz), [256..383]=bih_n, [384..511]=bhh_n
// ---------------------------------------------------------------------------
__global__ void pack_kernel(const float* __restrict__ Wm,
                            const float* __restrict__ Wih, const float* __restrict__ Whh,
                            const float* __restrict__ bih, const float* __restrict__ bhh,
                            bf16_t* __restrict__ Wrz, bf16_t* __restrict__ Win,
                            bf16_t* __restrict__ Whn, bf16_t* __restrict__ WmP,
                            float* __restrict__ bc)
{
    int tid = blockIdx.x * 256 + threadIdx.x;
    if (tid < 65536) {                         // Wrz
        int e = tid & 7, l = (tid >> 3) & 63, ks = (tid >> 9) & 15, ct = tid >> 13;
        int col = ct * 32 + (l & 31);          // 0..255
        int k   = ks * 16 + ((l >> 5) << 3) + e;   // 0..255
        float v = (k < 128) ? Wih[col * HID + k] : Whh[col * HID + (k - 128)];
        Wrz[tid] = (bf16_t)v;
    } else if (tid < 81920) {                  // Win
        int u = tid - 65536;
        int e = u & 7, l = (u >> 3) & 63, ks = (u >> 9) & 7, ct = u >> 12;
        int col = ct * 32 + (l & 31);
        int k   = ks * 16 + ((l >> 5) << 3) + e;
        Win[u] = (bf16_t)Wih[(256 + col) * HID + k];
    } else if (tid < 98304) {                  // Whn
        int u = tid - 81920;
        int e = u & 7, l = (u >> 3) & 63, ks = (u >> 9) & 7, ct = u >> 12;
        int col = ct * 32 + (l & 31);
        int k   = ks * 16 + ((l >> 5) << 3) + e;
        Whn[u] = (bf16_t)Whh[(256 + col) * HID + k];
    } else if (tid < 106496) {                 // WmP
        int u = tid - 98304;
        int e = u & 7, l = (u >> 3) & 63, ks = (u >> 9) & 3, ct = u >> 11;
        int col = ct * 32 + (l & 31);
        int k   = ks * 16 + ((l >> 5) << 3) + e;
        WmP[u] = (bf16_t)Wm[col * INDIM + k];
    } else if (tid < 107008) {                 // bc
        int j = tid - 106496;
        float v;
        if (j < 256)      v = bih[j] + bhh[j];
        else if (j < 384) v = bih[j];
        else              v = bhh[j - 128];
        bc[j] = v;
    }
}

// ---------------------------------------------------------------------------
// Persistent GRU: 256 blocks x 256 threads (4 waves); block owns 64 rows for
// all 24 steps. h carried in fp32 registers; per-step bf16 copy via LDS for
// the MFMA A-operand. Wave w: emb coltile w; rz coltiles {w, w+4}; in/hn
// coltile w; rows = 2 rowtiles of 32.
// ---------------------------------------------------------------------------
__global__ __launch_bounds__(256, 1) void gru_all(
    const float*  __restrict__ x, float* __restrict__ out,
    const bf16_t* __restrict__ Wrz, const bf16_t* __restrict__ Win,
    const bf16_t* __restrict__ Whn, const bf16_t* __restrict__ WmP,
    const float*  __restrict__ bc,  const float* __restrict__ bm)
{
    __shared__ __align__(16) char xs0[16384], xs1[16384];
    __shared__ __align__(16) char es [16384];
    __shared__ __align__(16) char hs0[16384], hs1[16384];

    const int tid = threadIdx.x;
    const int l   = tid & 63;
    const int w   = tid >> 6;
    const int r0  = blockIdx.x * 64;
    const int b   = r0 >> 9;
    const int n0  = r0 & (NB - 1);
    const float* xbase = x + ((size_t)b * T_STEPS * NB + n0) * INDIM;

    // zero hs0 (h(0) = 0)
    #pragma unroll
    for (int c0 = 0; c0 < 4; ++c0)
        ((uint4*)hs0)[c0 * 256 + tid] = make_uint4(0, 0, 0, 0);

    // stage xs0 for t=0 (fp32 -> bf16, 16B-slot XOR swizzle on row&15)
    {
        const float4* xsrc = (const float4*)xbase;
        #pragma unroll
        for (int c0 = 0; c0 < 4; ++c0) {
            int f = c0 * 256 + tid, row = f >> 4, k4 = f & 15;
            float4 v = xsrc[f];
            union { bf16_t h[4]; unsigned u[2]; } p;
            p.h[0] = (bf16_t)v.x; p.h[1] = (bf16_t)v.y;
            p.h[2] = (bf16_t)v.z; p.h[3] = (bf16_t)v.w;
            *(uint2*)(xs0 + row * 256 + ((k4 * 8) ^ ((row & 15) << 4))) = make_uint2(p.u[0], p.u[1]);
        }
    }

    const int jh  = w * 32 + (l & 31);
    const float bRr = bc[jh], bRz = bc[128 + jh], bIN = bc[256 + jh], bHN = bc[384 + jh];
    const float bmv = bm[jh];
    const int rA0 = l & 31, rA1 = 32 + rA0;
    const int sw0 = (rA0 & 15) << 4;          // rows r and r+32 share the swizzle
    const int hi  = (l >> 5);                 // k-half select

    f32x16 h0 = {}, h1 = {};                  // fp32 hidden state, 2 rowtiles

    auto step = [&](int t, const char* xsC, char* xsN, const char* hsC, char* hsN) {
        __syncthreads();                      // xsC/hsC ready; prev es reads done

        // ---- phase A: emb = relu(x @ Wm^T + bm), coltile w
        f32x16 aA0 = {}, aA1 = {};
        #pragma unroll
        for (int ks = 0; ks < 4; ++ks) {
            bf16x8 bfr = *(const bf16x8*)(WmP + (w * 4 + ks) * 512 + l * 8);
            int off = ((ks * 2 + hi) * 16) ^ sw0;
            bf16x8 a0 = *(const bf16x8*)(xsC + rA0 * 256 + off);
            bf16x8 a1 = *(const bf16x8*)(xsC + rA1 * 256 + off);
            aA0 = __builtin_amdgcn_mfma_f32_32x32x16_bf16(a0, bfr, aA0, 0, 0, 0);
            aA1 = __builtin_amdgcn_mfma_f32_32x32x16_bf16(a1, bfr, aA1, 0, 0, 0);
        }
        #pragma unroll
        for (int q = 0; q < 16; ++q) {
            int rl = (q & 3) + ((q >> 2) << 3) + (hi << 2);
            int sb = (jh * 2) ^ ((rl & 15) << 4);
            *(bf16_t*)(es + rl * 256 + sb)        = (bf16_t)fmaxf(aA0[q] + bmv, 0.f);
            *(bf16_t*)(es + (rl + 32) * 256 + sb) = (bf16_t)fmaxf(aA1[q] + bmv, 0.f);
        }

        // ---- prefetch x(t+1) into registers (consumed after next barrier)
        int tn = (t + 1 < T_STEPS) ? t + 1 : T_STEPS - 1;
        const float4* xp = (const float4*)(xbase + (size_t)tn * NB * INDIM);
        float4 pf0 = xp[0 * 256 + tid], pf1 = xp[1 * 256 + tid];
        float4 pf2 = xp[2 * 256 + tid], pf3 = xp[3 * 256 + tid];

        __syncthreads();                      // es ready

        // ---- phase B: rz (K=256 over [emb|h]), in (K=128 emb), hn (K=128 h)
        f32x16 rz00 = {}, rz01 = {}, rz10 = {}, rz11 = {};
        f32x16 in0 = {}, in1 = {}, hn0 = {}, hn1 = {};
        #pragma unroll
        for (int kk = 0; kk < 8; ++kk) {
            int off = ((kk * 2 + hi) * 16) ^ sw0;
            bf16x8 aE0 = *(const bf16x8*)(es  + rA0 * 256 + off);
            bf16x8 aE1 = *(const bf16x8*)(es  + rA1 * 256 + off);
            bf16x8 aH0 = *(const bf16x8*)(hsC + rA0 * 256 + off);
            bf16x8 aH1 = *(const bf16x8*)(hsC + rA1 * 256 + off);
            bf16x8 bE0 = *(const bf16x8*)(Wrz + ((w    ) * 16 + kk    ) * 512 + l * 8);
            bf16x8 bE1 = *(const bf16x8*)(Wrz + ((w + 4) * 16 + kk    ) * 512 + l * 8);
            bf16x8 bH0 = *(const bf16x8*)(Wrz + ((w    ) * 16 + 8 + kk) * 512 + l * 8);
            bf16x8 bH1 = *(const bf16x8*)(Wrz + ((w + 4) * 16 + 8 + kk) * 512 + l * 8);
            bf16x8 bI  = *(const bf16x8*)(Win + (w * 8 + kk) * 512 + l * 8);
            bf16x8 bN  = *(const bf16x8*)(Whn + (w * 8 + kk) * 512 + l * 8);
            rz00 = __builtin_amdgcn_mfma_f32_32x32x16_bf16(aE0, bE0, rz00, 0, 0, 0);
            rz01 = __builtin_amdgcn_mfma_f32_32x32x16_bf16(aE1, bE0, rz01, 0, 0, 0);
            rz10 = __builtin_amdgcn_mfma_f32_32x32x16_bf16(aE0, bE1, rz10, 0, 0, 0);
            rz11 = __builtin_amdgcn_mfma_f32_32x32x16_bf16(aE1, bE1, rz11, 0, 0, 0);
            rz00 = __builtin_amdgcn_mfma_f32_32x32x16_bf16(aH0, bH0, rz00, 0, 0, 0);
            rz01 = __builtin_amdgcn_mfma_f32_32x32x16_bf16(aH1, bH0, rz01, 0, 0, 0);
            rz10 = __builtin_amdgcn_mfma_f32_32x32x16_bf16(aH0, bH1, rz10, 0, 0, 0);
            rz11 = __builtin_amdgcn_mfma_f32_32x32x16_bf16(aH1, bH1, rz11, 0, 0, 0);
            in0  = __builtin_amdgcn_mfma_f32_32x32x16_bf16(aE0, bI,  in0, 0, 0, 0);
            in1  = __builtin_amdgcn_mfma_f32_32x32x16_bf16(aE1, bI,  in1, 0, 0, 0);
            hn0  = __builtin_amdgcn_mfma_f32_32x32x16_bf16(aH0, bN,  hn0, 0, 0, 0);
            hn1  = __builtin_amdgcn_mfma_f32_32x32x16_bf16(aH1, bN,  hn1, 0, 0, 0);
        }

        // ---- phase C: gates (lane-local), h update, write hsN (bf16) + xsN
        #pragma unroll
        for (int q = 0; q < 16; ++q) {
            int rl = (q & 3) + ((q >> 2) << 3) + (hi << 2);
            int sb = (jh * 2) ^ ((rl & 15) << 4);
            float r0g = sigm_(rz00[q] + bRr);
            float z0g = sigm_(rz10[q] + bRz);
            float n0g = tanh_(in0[q] + bIN + r0g * (hn0[q] + bHN));
            float hv0 = (1.f - z0g) * n0g + z0g * h0[q];
            h0[q] = hv0;
            *(bf16_t*)(hsN + rl * 256 + sb) = (bf16_t)hv0;
            float r1g = sigm_(rz01[q] + bRr);
            float z1g = sigm_(rz11[q] + bRz);
            float n1g = tanh_(in1[q] + bIN + r1g * (hn1[q] + bHN));
            float hv1 = (1.f - z1g) * n1g + z1g * h1[q];
            h1[q] = hv1;
            *(bf16_t*)(hsN + (rl + 32) * 256 + sb) = (bf16_t)hv1;
        }
        {   // write prefetched x(t+1) into xsN
            #define PF_ST(PF, C0) { \
                int f = (C0) * 256 + tid, row = f >> 4, k4 = f & 15; \
                union { bf16_t h[4]; unsigned u[2]; } p; \
                p.h[0] = (bf16_t)(PF).x; p.h[1] = (bf16_t)(PF).y; \
                p.h[2] = (bf16_t)(PF).z; p.h[3] = (bf16_t)(PF).w; \
                *(uint2*)(xsN + row * 256 + ((k4 * 8) ^ ((row & 15) << 4))) = make_uint2(p.u[0], p.u[1]); }
            PF_ST(pf0, 0) PF_ST(pf1, 1) PF_ST(pf2, 2) PF_ST(pf3, 3)
            #undef PF_ST
        }
    };

    for (int t = 0; t < T_STEPS; t += 2) {
        step(t,     xs0, xs1, hs0, hs1);
        step(t + 1, xs1, xs0, hs1, hs0);
    }

    // ---- final store (fp32) straight from registers
    #pragma unroll
    for (int q = 0; q < 16; ++q) {
        int rl = (q & 3) + ((q >> 2) << 3) + (hi << 2);
        out[(size_t)(r0 + rl) * HID + jh]      = h0[q];
        out[(size_t)(r0 + 32 + rl) * HID + jh] = h1[q];
    }
}

// ---------------------------------------------------------------------------
extern "C" void kernel_launch(void* const* d_in, const int* in_sizes, int n_in,
                              void* d_out, int out_size, void* d_ws, size_t ws_size,
                              hipStream_t stream)
{
    const float* x   = (const float*)d_in[0];
    const float* Wm  = (const float*)d_in[1];
    const float* bm  = (const float*)d_in[2];
    const float* Wih = (const float*)d_in[3];
    const float* Whh = (const float*)d_in[4];
    const float* bih = (const float*)d_in[5];
    const float* bhh = (const float*)d_in[6];

    char* ws = (char*)d_ws;
    bf16_t* Wrz = (bf16_t*)(ws);                 // 131072 B
    bf16_t* Win = (bf16_t*)(ws + 131072);        //  32768 B
    bf16_t* Whn = (bf16_t*)(ws + 163840);        //  32768 B
    bf16_t* WmP = (bf16_t*)(ws + 196608);        //  16384 B
    float*  bcp = (float*) (ws + 212992);        //   2048 B

    pack_kernel<<<418, 256, 0, stream>>>(Wm, Wih, Whh, bih, bhh, Wrz, Win, Whn, WmP, bcp);
    gru_all<<<256, 256, 0, stream>>>(x, (float*)d_out, Wrz, Win, Whn, WmP, bcp, bm);
}